// Round 6
// baseline (802.336 us; speedup 1.0000x reference)
//
#include <hip/hip_runtime.h>
#include <hip/hip_fp16.h>

#define RANK   64
#define VOCAB  32768
#define BATCH  2048
#define SEQLEN 256
#define DEPTH  4   // pipeline depth in steps (slots); 3 in flight

typedef __attribute__((ext_vector_type(8))) unsigned short ushort8; // 16B = 8 halves

// ---------------------------------------------------------------------------
// Kernel 1: ws[v][g][s][k] = (half)( core[8g+k][v][s]^2 )
// One ushort8 (16B) per thread. For fixed (v,g,k), consecutive s -> coalesced.
// ---------------------------------------------------------------------------
__global__ __launch_bounds__(256) void squash_kernel(const float* __restrict__ core,
                                                     ushort8* __restrict__ ws8) {
    int o = blockIdx.x * 256 + threadIdx.x;
    int v = o >> 9;
    int g = (o >> 6) & 7;
    int s = o & 63;
    ushort8 outv;
#pragma unroll
    for (int k = 0; k < 8; ++k) {
        int r = g * 8 + k;
        float c = core[((size_t)r * VOCAB + v) * RANK + s];
        __half h = __float2half(c * c);
        outv[k] = __builtin_bit_cast(unsigned short, h);
    }
    ws8[o] = outv;
}

// ---------------------------------------------------------------------------
// Direct global->LDS DMA, 16B per lane. LDS dest is wave-uniform base
// + lane*16 (hardware rule); global src is per-lane.
// ---------------------------------------------------------------------------
__device__ __forceinline__ void gload16(const void* g, void* l) {
    __builtin_amdgcn_global_load_lds(
        (const __attribute__((address_space(1))) void*)g,
        (__attribute__((address_space(3))) void*)l, 16, 0, 0);
}

// ---------------------------------------------------------------------------
// Kernel 2: one wave per block (64 threads), one batch element per wave.
// LDS ring buffer of DEPTH matrix slots (8KB each). DMA staging 3 steps
// ahead; consumption gated by hand-counted s_waitcnt vmcnt(24).
//
// Ordering proof (WAR safety): at the end of each consume phase we emit
// lgkmcnt(0) + sched_barrier(0). The FMAs already force all ds_reads of
// slot j to COMPLETE (data in VGPRs) before the barrier; the next
// iteration's global_load_lds (which overwrites slot j at DEPTH=4) cannot
// be scheduled above the barrier, and its LDS write cannot land before its
// issue. RAW safety: vmcnt(24) retires the 8 oldest loads (slot j) before
// the ds_reads of slot j.
// ---------------------------------------------------------------------------
__global__ __launch_bounds__(64) void mps_fp16_lds_kernel(const int* __restrict__ y,
                                                          const float* __restrict__ alpha,
                                                          const float* __restrict__ beta,
                                                          const ushort8* __restrict__ ws8,
                                                          float* __restrict__ out) {
    __shared__ ushort8 sbuf[DEPTH][8][64]; // 32 KB -> 5 blocks/CU

    const int b    = blockIdx.x;
    const int lane = threadIdx.x; // 0..63
    const int* yrow = y + (size_t)b * SEQLEN;

    // lane L holds tokens y[b, 64c + L]
    int yr0 = yrow[0 * 64 + lane];
    int yr1 = yrow[1 * 64 + lane];
    int yr2 = yrow[2 * 64 + lane];
    int yr3 = yrow[3 * 64 + lane];

    float a  = alpha[lane];
    float bb = beta[lane];
    float l  = a * a;
    float b2 = bb * bb;

    // Force every compiler-tracked VMEM load to retire BEFORE the first DMA,
    // so the manual vmcnt counting below is exact.
    asm volatile("" :: "v"(yr1), "v"(yr2), "v"(yr3), "v"(b2), "v"(l));

    // prologue: stage steps 0..DEPTH-2 into slots 0..DEPTH-2
#pragma unroll
    for (int s = 0; s < DEPTH - 1; ++s) {
        int tok = __builtin_amdgcn_readlane(yr0, s);
        const ushort8* gp = ws8 + (size_t)tok * 512 + lane;
#pragma unroll
        for (int g = 0; g < 8; ++g) gload16(gp + g * 64, &sbuf[s][g][0]);
    }

#pragma unroll 1
    for (int t4 = 0; t4 < SEQLEN / 4; ++t4) {
#pragma unroll
        for (int j = 0; j < 4; ++j) {
            // consume step s = 4*t4 + j (slot j); stage step s+3 (slot (j+3)&3)
            int s  = 4 * t4 + j;
            int kk = s + (DEPTH - 1);
            kk = (kk > SEQLEN - 1) ? (SEQLEN - 1) : kk; // tail: re-stage token 255
            int c  = kk >> 6;
            int yy = (c == 0) ? yr0 : (c == 1) ? yr1 : (c == 2) ? yr2 : yr3;
            int tok = __builtin_amdgcn_readlane(yy, kk & 63);
            const ushort8* gp = ws8 + (size_t)tok * 512 + lane;
#pragma unroll
            for (int g = 0; g < 8; ++g)
                gload16(gp + g * 64, &sbuf[(j + DEPTH - 1) & 3][g][0]);

            // steps s+1,s+2,s+3 (24 loads) stay in flight; step s is ready
            asm volatile("s_waitcnt vmcnt(24)" ::: "memory");
            __builtin_amdgcn_sched_barrier(0);

            float acc0 = 0.f, acc1 = 0.f, acc2 = 0.f, acc3 = 0.f;
#pragma unroll
            for (int g = 0; g < 8; ++g) {
                ushort8 m = sbuf[j][g][lane]; // ds_read_b128, conflict-free
#pragma unroll
                for (int k = 0; k < 8; ++k) {
                    const int r = g * 8 + k;
                    float lr = __uint_as_float(
                        __builtin_amdgcn_readlane(__float_as_uint(l), r));
                    __half h = __builtin_bit_cast(__half, (unsigned short)m[k]);
                    float mv = __half2float(h);
                    if ((k & 3) == 0)      acc0 = fmaf(lr, mv, acc0);
                    else if ((k & 3) == 1) acc1 = fmaf(lr, mv, acc1);
                    else if ((k & 3) == 2) acc2 = fmaf(lr, mv, acc2);
                    else                   acc3 = fmaf(lr, mv, acc3);
                }
            }
            l = (acc0 + acc1) + (acc2 + acc3);

            // Close the consume phase: all ds_reads of slot j have completed
            // (FMA data dependency); nothing from the next iteration may be
            // scheduled above this point. Kills the WAR race on slot reuse.
            asm volatile("s_waitcnt lgkmcnt(0)" ::: "memory");
            __builtin_amdgcn_sched_barrier(0);
        }
    }

    float v = l * b2;
#pragma unroll
    for (int off = 32; off > 0; off >>= 1) v += __shfl_xor(v, off, 64);
    if (lane == 0) out[b] = v;
}

// ---------------------------------------------------------------------------
// Fallback (exact f32, direct gather from core) if ws is too small.
// ---------------------------------------------------------------------------
__global__ __launch_bounds__(256) void mps_f32_kernel(const int* __restrict__ y,
                                                      const float* __restrict__ alpha,
                                                      const float* __restrict__ beta,
                                                      const float* __restrict__ core,
                                                      float* __restrict__ out) {
    int b    = (blockIdx.x * 256 + threadIdx.x) >> 6;
    int lane = threadIdx.x & 63;
    const int* yrow = y + (size_t)b * SEQLEN;

    float a = alpha[lane];
    float l = a * a;

#pragma unroll 1
    for (int t = 0; t < SEQLEN; ++t) {
        int tok = __builtin_amdgcn_readfirstlane(yrow[t]);
        const float* p = core + (size_t)tok * RANK + lane;
        float acc[4] = {0.f, 0.f, 0.f, 0.f};
#pragma unroll
        for (int r = 0; r < RANK; ++r) {
            float m  = p[(size_t)r * (VOCAB * RANK)];
            float lr = __uint_as_float(
                __builtin_amdgcn_readlane(__float_as_uint(l), r));
            acc[r & 3] = fmaf(lr, m * m, acc[r & 3]);
        }
        l = (acc[0] + acc[1]) + (acc[2] + acc[3]);
    }

    float bb = beta[lane];
    float v  = l * bb * bb;
#pragma unroll
    for (int off = 32; off > 0; off >>= 1) v += __shfl_xor(v, off, 64);
    if (lane == 0) out[b] = v;
}

extern "C" void kernel_launch(void* const* d_in, const int* in_sizes, int n_in,
                              void* d_out, int out_size, void* d_ws, size_t ws_size,
                              hipStream_t stream) {
    const int*   y     = (const int*)d_in[0];
    const float* alpha = (const float*)d_in[1];
    const float* beta  = (const float*)d_in[2];
    const float* core  = (const float*)d_in[3];
    float*       out   = (float*)d_out;

    const size_t need = (size_t)VOCAB * RANK * RANK * sizeof(unsigned short); // 256 MiB

    if (ws_size >= need) {
        int chunks = VOCAB * 8 * 64;
        squash_kernel<<<chunks / 256, 256, 0, stream>>>(core, (ushort8*)d_ws);
        mps_fp16_lds_kernel<<<BATCH, 64, 0, stream>>>(
            y, alpha, beta, (const ushort8*)d_ws, out);
    } else {
        mps_f32_kernel<<<(BATCH * 64) / 256, 256, 0, stream>>>(
            y, alpha, beta, core, out);
    }
}

// Round 7
// 772.931 us; speedup vs baseline: 1.0380x; 1.0380x over previous
//
#include <hip/hip_runtime.h>
#include <hip/hip_fp16.h>

#define RANK   64
#define VOCAB  32768
#define BATCH  2048
#define SEQLEN 256
#define DEPTH  4   // pipeline depth in steps (slots); 3 in flight

typedef __attribute__((ext_vector_type(8))) unsigned short ushort8; // 16B = 8 halves

// ---------------------------------------------------------------------------
// Kernel 1: ws[v][g][s][k] = (half)( core[8g+k][v][s]^2 )
// One ushort8 (16B) per thread. For fixed (v,g,k), consecutive s -> coalesced.
// core reads are NONTEMPORAL: the 512MB read stream must not evict the
// freshly written ws lines from L3 (ws == 256MB == L3 size; the main kernel
// wants the whole table resident). ws stores stay normal (write-allocate).
// ---------------------------------------------------------------------------
__global__ __launch_bounds__(256) void squash_kernel(const float* __restrict__ core,
                                                     ushort8* __restrict__ ws8) {
    int o = blockIdx.x * 256 + threadIdx.x;
    int v = o >> 9;
    int g = (o >> 6) & 7;
    int s = o & 63;
    ushort8 outv;
#pragma unroll
    for (int k = 0; k < 8; ++k) {
        int r = g * 8 + k;
        float c = __builtin_nontemporal_load(
            &core[((size_t)r * VOCAB + v) * RANK + s]);
        __half h = __float2half(c * c);
        outv[k] = __builtin_bit_cast(unsigned short, h);
    }
    ws8[o] = outv;
}

// ---------------------------------------------------------------------------
// Direct global->LDS DMA, 16B per lane. LDS dest is wave-uniform base
// + lane*16 (hardware rule); global src is per-lane.
// ---------------------------------------------------------------------------
__device__ __forceinline__ void gload16(const void* g, void* l) {
    __builtin_amdgcn_global_load_lds(
        (const __attribute__((address_space(1))) void*)g,
        (__attribute__((address_space(3))) void*)l, 16, 0, 0);
}

// ---------------------------------------------------------------------------
// Kernel 2: one wave per block (64 threads), one batch element per wave.
// LDS ring buffer of DEPTH matrix slots (8KB each). DMA staging 3 steps
// ahead; consumption gated by hand-counted s_waitcnt vmcnt(24).
//
// Ordering proof (WAR safety): at the end of each consume phase we emit
// lgkmcnt(0) + sched_barrier(0). The FMAs already force all ds_reads of
// slot j to COMPLETE (data in VGPRs) before the barrier; the next
// iteration's global_load_lds (which overwrites slot j at DEPTH=4) cannot
// be scheduled above the barrier, and its LDS write cannot land before its
// issue. RAW safety: vmcnt(24) retires the 8 oldest loads (slot j) before
// the ds_reads of slot j.
// ---------------------------------------------------------------------------
__global__ __launch_bounds__(64) void mps_fp16_lds_kernel(const int* __restrict__ y,
                                                          const float* __restrict__ alpha,
                                                          const float* __restrict__ beta,
                                                          const ushort8* __restrict__ ws8,
                                                          float* __restrict__ out) {
    __shared__ ushort8 sbuf[DEPTH][8][64]; // 32 KB -> 5 blocks/CU

    const int b    = blockIdx.x;
    const int lane = threadIdx.x; // 0..63
    const int* yrow = y + (size_t)b * SEQLEN;

    // lane L holds tokens y[b, 64c + L]
    int yr0 = yrow[0 * 64 + lane];
    int yr1 = yrow[1 * 64 + lane];
    int yr2 = yrow[2 * 64 + lane];
    int yr3 = yrow[3 * 64 + lane];

    float a  = alpha[lane];
    float bb = beta[lane];
    float l  = a * a;
    float b2 = bb * bb;

    // Force every compiler-tracked VMEM load to retire BEFORE the first DMA,
    // so the manual vmcnt counting below is exact.
    asm volatile("" :: "v"(yr1), "v"(yr2), "v"(yr3), "v"(b2), "v"(l));

    // prologue: stage steps 0..DEPTH-2 into slots 0..DEPTH-2
#pragma unroll
    for (int s = 0; s < DEPTH - 1; ++s) {
        int tok = __builtin_amdgcn_readlane(yr0, s);
        const ushort8* gp = ws8 + (size_t)tok * 512 + lane;
#pragma unroll
        for (int g = 0; g < 8; ++g) gload16(gp + g * 64, &sbuf[s][g][0]);
    }

#pragma unroll 1
    for (int t4 = 0; t4 < SEQLEN / 4; ++t4) {
#pragma unroll
        for (int j = 0; j < 4; ++j) {
            // consume step s = 4*t4 + j (slot j); stage step s+3 (slot (j+3)&3)
            int s  = 4 * t4 + j;
            int kk = s + (DEPTH - 1);
            kk = (kk > SEQLEN - 1) ? (SEQLEN - 1) : kk; // tail: re-stage token 255
            int c  = kk >> 6;
            int yy = (c == 0) ? yr0 : (c == 1) ? yr1 : (c == 2) ? yr2 : yr3;
            int tok = __builtin_amdgcn_readlane(yy, kk & 63);
            const ushort8* gp = ws8 + (size_t)tok * 512 + lane;
#pragma unroll
            for (int g = 0; g < 8; ++g)
                gload16(gp + g * 64, &sbuf[(j + DEPTH - 1) & 3][g][0]);

            // steps s+1,s+2,s+3 (24 loads) stay in flight; step s is ready
            asm volatile("s_waitcnt vmcnt(24)" ::: "memory");
            __builtin_amdgcn_sched_barrier(0);

            float acc0 = 0.f, acc1 = 0.f, acc2 = 0.f, acc3 = 0.f;
#pragma unroll
            for (int g = 0; g < 8; ++g) {
                ushort8 m = sbuf[j][g][lane]; // ds_read_b128, conflict-free
#pragma unroll
                for (int k = 0; k < 8; ++k) {
                    const int r = g * 8 + k;
                    float lr = __uint_as_float(
                        __builtin_amdgcn_readlane(__float_as_uint(l), r));
                    __half h = __builtin_bit_cast(__half, (unsigned short)m[k]);
                    float mv = __half2float(h);
                    if ((k & 3) == 0)      acc0 = fmaf(lr, mv, acc0);
                    else if ((k & 3) == 1) acc1 = fmaf(lr, mv, acc1);
                    else if ((k & 3) == 2) acc2 = fmaf(lr, mv, acc2);
                    else                   acc3 = fmaf(lr, mv, acc3);
                }
            }
            l = (acc0 + acc1) + (acc2 + acc3);

            // Close the consume phase: all ds_reads of slot j have completed
            // (FMA data dependency); nothing from the next iteration may be
            // scheduled above this point. Kills the WAR race on slot reuse.
            asm volatile("s_waitcnt lgkmcnt(0)" ::: "memory");
            __builtin_amdgcn_sched_barrier(0);
        }
    }

    float v = l * b2;
#pragma unroll
    for (int off = 32; off > 0; off >>= 1) v += __shfl_xor(v, off, 64);
    if (lane == 0) out[b] = v;
}

// ---------------------------------------------------------------------------
// Fallback (exact f32, direct gather from core) if ws is too small.
// ---------------------------------------------------------------------------
__global__ __launch_bounds__(256) void mps_f32_kernel(const int* __restrict__ y,
                                                      const float* __restrict__ alpha,
                                                      const float* __restrict__ beta,
                                                      const float* __restrict__ core,
                                                      float* __restrict__ out) {
    int b    = (blockIdx.x * 256 + threadIdx.x) >> 6;
    int lane = threadIdx.x & 63;
    const int* yrow = y + (size_t)b * SEQLEN;

    float a = alpha[lane];
    float l = a * a;

#pragma unroll 1
    for (int t = 0; t < SEQLEN; ++t) {
        int tok = __builtin_amdgcn_readfirstlane(yrow[t]);
        const float* p = core + (size_t)tok * RANK + lane;
        float acc[4] = {0.f, 0.f, 0.f, 0.f};
#pragma unroll
        for (int r = 0; r < RANK; ++r) {
            float m  = p[(size_t)r * (VOCAB * RANK)];
            float lr = __uint_as_float(
                __builtin_amdgcn_readlane(__float_as_uint(l), r));
            acc[r & 3] = fmaf(lr, m * m, acc[r & 3]);
        }
        l = (acc[0] + acc[1]) + (acc[2] + acc[3]);
    }

    float bb = beta[lane];
    float v  = l * bb * bb;
#pragma unroll
    for (int off = 32; off > 0; off >>= 1) v += __shfl_xor(v, off, 64);
    if (lane == 0) out[b] = v;
}

extern "C" void kernel_launch(void* const* d_in, const int* in_sizes, int n_in,
                              void* d_out, int out_size, void* d_ws, size_t ws_size,
                              hipStream_t stream) {
    const int*   y     = (const int*)d_in[0];
    const float* alpha = (const float*)d_in[1];
    const float* beta  = (const float*)d_in[2];
    const float* core  = (const float*)d_in[3];
    float*       out   = (float*)d_out;

    const size_t need = (size_t)VOCAB * RANK * RANK * sizeof(unsigned short); // 256 MiB

    if (ws_size >= need) {
        int chunks = VOCAB * 8 * 64;
        squash_kernel<<<chunks / 256, 256, 0, stream>>>(core, (ushort8*)d_ws);
        mps_fp16_lds_kernel<<<BATCH, 64, 0, stream>>>(
            y, alpha, beta, (const ushort8*)d_ws, out);
    } else {
        mps_f32_kernel<<<(BATCH * 64) / 256, 256, 0, stream>>>(
            y, alpha, beta, core, out);
    }
}

// Round 8
// 704.711 us; speedup vs baseline: 1.1385x; 1.0968x over previous
//
#include <hip/hip_runtime.h>

#define RANK   64
#define VOCAB  32768
#define BATCH  2048
#define SEQLEN 256
#define DEPTH  4   // pipeline slots; 3 steps in flight; 7 loads/step -> vmcnt(21)

typedef __attribute__((ext_vector_type(4))) unsigned int uint4v;

// ws layout:
//   region A (u12 data): per token v, 6 chunks x 1KB. chunk c, lane s holds
//     dwords D[4c..4c+3] of lane s's 24-dword blob. Blob: group j (entries
//     r=8j..8j+7) packed LSB-first into D[3j],D[3j+1],D[3j+2]:
//       D0 = e0 | e1<<12 | e2<<24
//       D1 = e2>>8 | e3<<4 | e4<<16 | e5<<28
//       D2 = e5>>4 | e6<<8 | e7<<20
//     entry (r, s) of matrix v = u12 value; M[r][s] = scale[v][r] * u12.
//   region B (scales): f32 ws_sc[v][r], 256 B per token.
#define WS_DATA_BYTES ((size_t)VOCAB * 6144)
#define WS_SC_BYTES   ((size_t)VOCAB * 256)

// ---------------------------------------------------------------------------
// Kernel 1: squash+quantize. One wave per matrix. Lane s owns column s
// (entries r=0..63 in registers). Row maxima via padded LDS transpose.
// ---------------------------------------------------------------------------
__global__ __launch_bounds__(64) void squash12_kernel(const float* __restrict__ core,
                                                      unsigned int* __restrict__ wsd,
                                                      float* __restrict__ wssc) {
    __shared__ float tsq[64 * 65]; // padded transpose: row r at tsq[r*65 + s]
    __shared__ float tinv[64];

    const int v = blockIdx.x;
    const int s = threadIdx.x; // 0..63 = column

    // read column s of matrix v (coalesced across lanes), square
    float sq[64];
#pragma unroll
    for (int r = 0; r < 64; ++r) {
        float c = __builtin_nontemporal_load(&core[((size_t)r * VOCAB + v) * RANK + s]);
        sq[r] = c * c;
    }
    // transpose into LDS (bank-conflict-free via +1 padding)
#pragma unroll
    for (int r = 0; r < 64; ++r) tsq[r * 65 + s] = sq[r];
    __syncthreads();

    // lane s computes rowmax of row s
    float mx = 0.f;
#pragma unroll
    for (int q = 0; q < 64; ++q) mx = fmaxf(mx, tsq[s * 65 + q]);
    float scale = mx * (1.0f / 4095.0f);
    float inv   = (mx > 0.f) ? (4095.0f / mx) : 0.f;
    wssc[(size_t)v * 64 + s] = scale;
    tinv[s] = inv;
    __syncthreads();

    // quantize own column (registers) with per-row inv, pack u12 -> 24 dwords
    unsigned int D[24];
#pragma unroll
    for (int j = 0; j < 8; ++j) {
        unsigned int e[8];
#pragma unroll
        for (int k = 0; k < 8; ++k) {
            float q = sq[8 * j + k] * tinv[8 * j + k];
            unsigned int u = (unsigned int)(q + 0.5f);
            e[k] = (u > 4095u) ? 4095u : u;
        }
        D[3 * j + 0] = e[0] | (e[1] << 12) | (e[2] << 24);
        D[3 * j + 1] = (e[2] >> 8) | (e[3] << 4) | (e[4] << 16) | (e[5] << 28);
        D[3 * j + 2] = (e[5] >> 4) | (e[6] << 8) | (e[7] << 20);
    }
    // store 6 chunks (coalesced 1KB per chunk across lanes)
    uint4v* dst = (uint4v*)wsd;
#pragma unroll
    for (int c = 0; c < 6; ++c) {
        uint4v w;
        w[0] = D[4 * c + 0]; w[1] = D[4 * c + 1];
        w[2] = D[4 * c + 2]; w[3] = D[4 * c + 3];
        dst[((size_t)v * 6 + c) * 64 + s] = w;
    }
}

// ---------------------------------------------------------------------------
// global->LDS DMA helpers (LDS dest = wave-uniform base + lane*size)
// ---------------------------------------------------------------------------
__device__ __forceinline__ void gload16(const void* g, void* l) {
    __builtin_amdgcn_global_load_lds(
        (const __attribute__((address_space(1))) void*)g,
        (__attribute__((address_space(3))) void*)l, 16, 0, 0);
}
__device__ __forceinline__ void gload4(const void* g, void* l) {
    __builtin_amdgcn_global_load_lds(
        (const __attribute__((address_space(1))) void*)g,
        (__attribute__((address_space(3))) void*)l, 4, 0, 0);
}

// ---------------------------------------------------------------------------
// Kernel 2: one wave per block, one batch element per wave. LDS ring of
// DEPTH slots (6.4 KB each: 6x1KB u12 data + 256B scales). 7 DMA loads per
// step, 3 steps in flight -> s_waitcnt vmcnt(21) gates consumption.
// WAR safety: lgkmcnt(0)+sched_barrier after consume (proven r6).
// ---------------------------------------------------------------------------
__global__ __launch_bounds__(64) void mps_u12_lds_kernel(const int* __restrict__ y,
                                                         const float* __restrict__ alpha,
                                                         const float* __restrict__ beta,
                                                         const unsigned int* __restrict__ wsd,
                                                         const float* __restrict__ wssc,
                                                         float* __restrict__ out) {
    __shared__ uint4v sdat[DEPTH][6][64]; // 24 KB
    __shared__ float  ssc[DEPTH][64];     // 1 KB

    const int b    = blockIdx.x;
    const int lane = threadIdx.x; // 0..63
    const int* yrow = y + (size_t)b * SEQLEN;

    int yr0 = yrow[0 * 64 + lane];
    int yr1 = yrow[1 * 64 + lane];
    int yr2 = yrow[2 * 64 + lane];
    int yr3 = yrow[3 * 64 + lane];

    float a  = alpha[lane];
    float bb = beta[lane];
    float l  = a * a;
    float b2 = bb * bb;

    // all compiler-tracked VMEM retired before the first DMA (exact vmcnt)
    asm volatile("" :: "v"(yr1), "v"(yr2), "v"(yr3), "v"(b2), "v"(l));

    const uint4v* wsd4 = (const uint4v*)wsd;

    // prologue: stage steps 0..2 into slots 0..2 (7 loads each)
#pragma unroll
    for (int s = 0; s < DEPTH - 1; ++s) {
        int tok = __builtin_amdgcn_readlane(yr0, s);
        const uint4v* gp = wsd4 + (size_t)tok * 384 + lane;
#pragma unroll
        for (int c = 0; c < 6; ++c) gload16(gp + c * 64, &sdat[s][c][0]);
        gload4(wssc + (size_t)tok * 64 + lane, &ssc[s][0]);
    }

#pragma unroll 1
    for (int t4 = 0; t4 < SEQLEN / 4; ++t4) {
#pragma unroll
        for (int j = 0; j < 4; ++j) {
            // consume step s = 4*t4+j (slot j); stage step s+3 (slot (j+3)&3)
            int s  = 4 * t4 + j;
            int kk = s + (DEPTH - 1);
            kk = (kk > SEQLEN - 1) ? (SEQLEN - 1) : kk; // tail restage, never consumed
            int c_  = kk >> 6;
            int yy  = (c_ == 0) ? yr0 : (c_ == 1) ? yr1 : (c_ == 2) ? yr2 : yr3;
            int tok = __builtin_amdgcn_readlane(yy, kk & 63);
            const uint4v* gp = wsd4 + (size_t)tok * 384 + lane;
#pragma unroll
            for (int c = 0; c < 6; ++c)
                gload16(gp + c * 64, &sdat[(j + DEPTH - 1) & 3][c][0]);
            gload4(wssc + (size_t)tok * 64 + lane, &ssc[(j + DEPTH - 1) & 3][0]);

            // 3 future steps (21 loads) stay in flight; slot j is ready
            asm volatile("s_waitcnt vmcnt(21)" ::: "memory");
            __builtin_amdgcn_sched_barrier(0);

            // pre-scale: lane r holds l_r * scale_r
            float ls = l * ssc[j][lane];

            unsigned int D[24];
#pragma unroll
            for (int c = 0; c < 6; ++c) {
                uint4v d = sdat[j][c][lane]; // ds_read_b128
                D[4 * c + 0] = d[0]; D[4 * c + 1] = d[1];
                D[4 * c + 2] = d[2]; D[4 * c + 3] = d[3];
            }

            float acc0 = 0.f, acc1 = 0.f, acc2 = 0.f, acc3 = 0.f;
#pragma unroll
            for (int jj = 0; jj < 8; ++jj) {
                unsigned int d0 = D[3 * jj], d1 = D[3 * jj + 1], d2 = D[3 * jj + 2];
                unsigned int e0 = d0 & 0xFFFu;
                unsigned int e1 = (d0 >> 12) & 0xFFFu;
                unsigned int e2 = ((d0 >> 24) | (d1 << 8)) & 0xFFFu;
                unsigned int e3 = (d1 >> 4) & 0xFFFu;
                unsigned int e4 = (d1 >> 16) & 0xFFFu;
                unsigned int e5 = ((d1 >> 28) | (d2 << 4)) & 0xFFFu;
                unsigned int e6 = (d2 >> 8) & 0xFFFu;
                unsigned int e7 = d2 >> 20;
                unsigned int ee[8] = {e0, e1, e2, e3, e4, e5, e6, e7};
#pragma unroll
                for (int k = 0; k < 8; ++k) {
                    const int r = 8 * jj + k;
                    float lr = __uint_as_float(
                        __builtin_amdgcn_readlane(__float_as_uint(ls), r));
                    float mv = (float)ee[k];
                    if ((k & 3) == 0)      acc0 = fmaf(lr, mv, acc0);
                    else if ((k & 3) == 1) acc1 = fmaf(lr, mv, acc1);
                    else if ((k & 3) == 2) acc2 = fmaf(lr, mv, acc2);
                    else                   acc3 = fmaf(lr, mv, acc3);
                }
            }
            l = (acc0 + acc1) + (acc2 + acc3);

            // close consume phase: ds_reads of slot j complete; next iter's
            // DMA cannot be scheduled above this point (WAR fence, r6-proven)
            asm volatile("s_waitcnt lgkmcnt(0)" ::: "memory");
            __builtin_amdgcn_sched_barrier(0);
        }
    }

    float v = l * b2;
#pragma unroll
    for (int off = 32; off > 0; off >>= 1) v += __shfl_xor(v, off, 64);
    if (lane == 0) out[b] = v;
}

// ---------------------------------------------------------------------------
// Fallback (exact f32, direct gather from core) if ws is too small.
// ---------------------------------------------------------------------------
__global__ __launch_bounds__(256) void mps_f32_kernel(const int* __restrict__ y,
                                                      const float* __restrict__ alpha,
                                                      const float* __restrict__ beta,
                                                      const float* __restrict__ core,
                                                      float* __restrict__ out) {
    int b    = (blockIdx.x * 256 + threadIdx.x) >> 6;
    int lane = threadIdx.x & 63;
    const int* yrow = y + (size_t)b * SEQLEN;

    float a = alpha[lane];
    float l = a * a;

#pragma unroll 1
    for (int t = 0; t < SEQLEN; ++t) {
        int tok = __builtin_amdgcn_readfirstlane(yrow[t]);
        const float* p = core + (size_t)tok * RANK + lane;
        float acc[4] = {0.f, 0.f, 0.f, 0.f};
#pragma unroll
        for (int r = 0; r < RANK; ++r) {
            float m  = p[(size_t)r * (VOCAB * RANK)];
            float lr = __uint_as_float(
                __builtin_amdgcn_readlane(__float_as_uint(l), r));
            acc[r & 3] = fmaf(lr, m * m, acc[r & 3]);
        }
        l = (acc[0] + acc[1]) + (acc[2] + acc[3]);
    }

    float bb = beta[lane];
    float v  = l * bb * bb;
#pragma unroll
    for (int off = 32; off > 0; off >>= 1) v += __shfl_xor(v, off, 64);
    if (lane == 0) out[b] = v;
}

extern "C" void kernel_launch(void* const* d_in, const int* in_sizes, int n_in,
                              void* d_out, int out_size, void* d_ws, size_t ws_size,
                              hipStream_t stream) {
    const int*   y     = (const int*)d_in[0];
    const float* alpha = (const float*)d_in[1];
    const float* beta  = (const float*)d_in[2];
    const float* core  = (const float*)d_in[3];
    float*       out   = (float*)d_out;

    const size_t need = WS_DATA_BYTES + WS_SC_BYTES; // 200 MiB

    if (ws_size >= need) {
        unsigned int* wsd  = (unsigned int*)d_ws;
        float*        wssc = (float*)((char*)d_ws + WS_DATA_BYTES);
        squash12_kernel<<<VOCAB, 64, 0, stream>>>(core, wsd, wssc);
        mps_u12_lds_kernel<<<BATCH, 64, 0, stream>>>(y, alpha, beta, wsd, wssc, out);
    } else {
        mps_f32_kernel<<<(BATCH * 64) / 256, 256, 0, stream>>>(
            y, alpha, beta, core, out);
    }
}

// Round 9
// 583.158 us; speedup vs baseline: 1.3758x; 1.2084x over previous
//
#include <hip/hip_runtime.h>

#define RANK   64
#define VOCAB  32768
#define BATCH  2048
#define SEQLEN 256

typedef __attribute__((ext_vector_type(4))) unsigned int uint4v;

// ws layout:
//   region A (u12 data): per token v, 6 chunks x 1KB (6144B, stride 384 uint4v).
//     chunk c, lane s holds dwords D[4c..4c+3] of lane s's 24-dword blob.
//     Group j (entries r=8j..8j+7) packed LSB-first into D[3j..3j+2].
//     entry (r,s) of matrix v: M[r][s] = scale[v][r] * u12.
//   region B (scales): f32 ws_sc[v][r], 256 B per token.
#define WS_DATA_BYTES ((size_t)VOCAB * 6144)
#define WS_SC_BYTES   ((size_t)VOCAB * 256)

// ---------------------------------------------------------------------------
// Kernel 1: squash+quantize. One wave per matrix. Lane s owns column s.
// Row maxima via padded LDS transpose. (unchanged from r8, proven)
// ---------------------------------------------------------------------------
__global__ __launch_bounds__(64) void squash12_kernel(const float* __restrict__ core,
                                                      unsigned int* __restrict__ wsd,
                                                      float* __restrict__ wssc) {
    __shared__ float tsq[64 * 65];
    __shared__ float tinv[64];

    const int v = blockIdx.x;
    const int s = threadIdx.x;

    float sq[64];
#pragma unroll
    for (int r = 0; r < 64; ++r) {
        float c = __builtin_nontemporal_load(&core[((size_t)r * VOCAB + v) * RANK + s]);
        sq[r] = c * c;
    }
#pragma unroll
    for (int r = 0; r < 64; ++r) tsq[r * 65 + s] = sq[r];
    __syncthreads();

    float mx = 0.f;
#pragma unroll
    for (int q = 0; q < 64; ++q) mx = fmaxf(mx, tsq[s * 65 + q]);
    float scale = mx * (1.0f / 4095.0f);
    float inv   = (mx > 0.f) ? (4095.0f / mx) : 0.f;
    wssc[(size_t)v * 64 + s] = scale;
    tinv[s] = inv;
    __syncthreads();

    unsigned int D[24];
#pragma unroll
    for (int j = 0; j < 8; ++j) {
        unsigned int e[8];
#pragma unroll
        for (int k = 0; k < 8; ++k) {
            float q = sq[8 * j + k] * tinv[8 * j + k];
            unsigned int u = (unsigned int)(q + 0.5f);
            e[k] = (u > 4095u) ? 4095u : u;
        }
        D[3 * j + 0] = e[0] | (e[1] << 12) | (e[2] << 24);
        D[3 * j + 1] = (e[2] >> 8) | (e[3] << 4) | (e[4] << 16) | (e[5] << 28);
        D[3 * j + 2] = (e[5] >> 4) | (e[6] << 8) | (e[7] << 20);
    }
    uint4v* dst = (uint4v*)wsd;
#pragma unroll
    for (int c = 0; c < 6; ++c) {
        uint4v w;
        w[0] = D[4 * c + 0]; w[1] = D[4 * c + 1];
        w[2] = D[4 * c + 2]; w[3] = D[4 * c + 3];
        dst[((size_t)v * 6 + c) * 64 + s] = w;
    }
}

// ---------------------------------------------------------------------------
// global->LDS DMA helpers
// ---------------------------------------------------------------------------
__device__ __forceinline__ void gload16(const void* g, void* l) {
    __builtin_amdgcn_global_load_lds(
        (const __attribute__((address_space(1))) void*)g,
        (__attribute__((address_space(3))) void*)l, 16, 0, 0);
}
__device__ __forceinline__ void gload4(const void* g, void* l) {
    __builtin_amdgcn_global_load_lds(
        (const __attribute__((address_space(1))) void*)g,
        (__attribute__((address_space(3))) void*)l, 4, 0, 0);
}

// ---------------------------------------------------------------------------
// Kernel 2: one wave per block, one batch element per wave. DEPTH=3 LDS ring
// (18.75 KB -> 8 blocks/CU, whole grid co-resident). 7 DMA loads/step,
// 2 steps in flight -> vmcnt(14). WAR safety: lgkmcnt(0)+sched_barrier
// after each consume (proven r6); RAW: counted vmcnt before consume.
// ---------------------------------------------------------------------------
__global__ __launch_bounds__(64) void mps_u12_lds_kernel(const int* __restrict__ y,
                                                         const float* __restrict__ alpha,
                                                         const float* __restrict__ beta,
                                                         const unsigned int* __restrict__ wsd,
                                                         const float* __restrict__ wssc,
                                                         float* __restrict__ out) {
    __shared__ uint4v sdat[3][6][64]; // 18 KB
    __shared__ float  ssc[3][64];     // 768 B

    const int b    = blockIdx.x;
    const int lane = threadIdx.x;
    const int* yrow = y + (size_t)b * SEQLEN;

    int yr0 = yrow[0 * 64 + lane];
    int yr1 = yrow[1 * 64 + lane];
    int yr2 = yrow[2 * 64 + lane];
    int yr3 = yrow[3 * 64 + lane];

    float a  = alpha[lane];
    float bb = beta[lane];
    float l  = a * a;
    float b2 = bb * bb;

    // all compiler-tracked VMEM retired before first DMA (exact vmcnt)
    asm volatile("" :: "v"(yr1), "v"(yr2), "v"(yr3), "v"(b2), "v"(l));

    const uint4v* wsd4 = (const uint4v*)wsd;

    auto stage = [&](int kk, int slot) {
        int c_  = kk >> 6;
        int yy  = (c_ == 0) ? yr0 : (c_ == 1) ? yr1 : (c_ == 2) ? yr2 : yr3;
        int tok = __builtin_amdgcn_readlane(yy, kk & 63);
        const uint4v* gp = wsd4 + (size_t)tok * 384 + lane;
#pragma unroll
        for (int c = 0; c < 6; ++c) gload16(gp + c * 64, &sdat[slot][c][0]);
        gload4(wssc + (size_t)tok * 64 + lane, &ssc[slot][0]);
    };

    auto consume = [&](int slot) {
        float ls = l * ssc[slot][lane];
        unsigned int D[24];
#pragma unroll
        for (int c = 0; c < 6; ++c) {
            uint4v d = sdat[slot][c][lane]; // ds_read_b128
            D[4 * c + 0] = d[0]; D[4 * c + 1] = d[1];
            D[4 * c + 2] = d[2]; D[4 * c + 3] = d[3];
        }
        float acc0 = 0.f, acc1 = 0.f, acc2 = 0.f, acc3 = 0.f;
#pragma unroll
        for (int jj = 0; jj < 8; ++jj) {
            unsigned int d0 = D[3 * jj], d1 = D[3 * jj + 1], d2 = D[3 * jj + 2];
            unsigned int ee[8];
            ee[0] = d0 & 0xFFFu;
            ee[1] = (d0 >> 12) & 0xFFFu;
            ee[2] = ((d0 >> 24) | (d1 << 8)) & 0xFFFu;
            ee[3] = (d1 >> 4) & 0xFFFu;
            ee[4] = (d1 >> 16) & 0xFFFu;
            ee[5] = ((d1 >> 28) | (d2 << 4)) & 0xFFFu;
            ee[6] = (d2 >> 8) & 0xFFFu;
            ee[7] = d2 >> 20;
#pragma unroll
            for (int k = 0; k < 8; ++k) {
                const int r = 8 * jj + k;
                float lr = __uint_as_float(
                    __builtin_amdgcn_readlane(__float_as_uint(ls), r));
                float mv = (float)ee[k];
                if ((k & 3) == 0)      acc0 = fmaf(lr, mv, acc0);
                else if ((k & 3) == 1) acc1 = fmaf(lr, mv, acc1);
                else if ((k & 3) == 2) acc2 = fmaf(lr, mv, acc2);
                else                   acc3 = fmaf(lr, mv, acc3);
            }
        }
        l = (acc0 + acc1) + (acc2 + acc3);
    };

    // prologue: stage steps 0,1 into slots 0,1 (14 loads outstanding)
    stage(0, 0);
    stage(1, 1);

#define STEP(S, SLOT, STSLOT)                                              \
    do {                                                                   \
        int kk = (S) + 2; kk = (kk > SEQLEN - 1) ? (SEQLEN - 1) : kk;      \
        stage(kk, (STSLOT));                                               \
        asm volatile("s_waitcnt vmcnt(14)" ::: "memory");                  \
        __builtin_amdgcn_sched_barrier(0);                                 \
        consume((SLOT));                                                   \
        asm volatile("s_waitcnt lgkmcnt(0)" ::: "memory");                 \
        __builtin_amdgcn_sched_barrier(0);                                 \
    } while (0)

#pragma unroll 1
    for (int t3 = 0; t3 < 85; ++t3) { // steps 0..254
        int s0 = 3 * t3;
        STEP(s0 + 0, 0, 2);
        STEP(s0 + 1, 1, 0);
        STEP(s0 + 2, 2, 1);
    }
    // epilogue: step 255 lives in slot 0 (staged at s=253); drop the
    // in-flight duplicate stage from s=254 below it.
    asm volatile("s_waitcnt vmcnt(7)" ::: "memory");
    __builtin_amdgcn_sched_barrier(0);
    consume(0);
#undef STEP

    float v = l * b2;
#pragma unroll
    for (int off = 32; off > 0; off >>= 1) v += __shfl_xor(v, off, 64);
    if (lane == 0) out[b] = v;
}

// ---------------------------------------------------------------------------
// Fallback (exact f32, direct gather from core) if ws is too small.
// ---------------------------------------------------------------------------
__global__ __launch_bounds__(256) void mps_f32_kernel(const int* __restrict__ y,
                                                      const float* __restrict__ alpha,
                                                      const float* __restrict__ beta,
                                                      const float* __restrict__ core,
                                                      float* __restrict__ out) {
    int b    = (blockIdx.x * 256 + threadIdx.x) >> 6;
    int lane = threadIdx.x & 63;
    const int* yrow = y + (size_t)b * SEQLEN;

    float a = alpha[lane];
    float l = a * a;

#pragma unroll 1
    for (int t = 0; t < SEQLEN; ++t) {
        int tok = __builtin_amdgcn_readfirstlane(yrow[t]);
        const float* p = core + (size_t)tok * RANK + lane;
        float acc[4] = {0.f, 0.f, 0.f, 0.f};
#pragma unroll
        for (int r = 0; r < RANK; ++r) {
            float m  = p[(size_t)r * (VOCAB * RANK)];
            float lr = __uint_as_float(
                __builtin_amdgcn_readlane(__float_as_uint(l), r));
            acc[r & 3] = fmaf(lr, m * m, acc[r & 3]);
        }
        l = (acc[0] + acc[1]) + (acc[2] + acc[3]);
    }

    float bb = beta[lane];
    float v  = l * bb * bb;
#pragma unroll
    for (int off = 32; off > 0; off >>= 1) v += __shfl_xor(v, off, 64);
    if (lane == 0) out[b] = v;
}

extern "C" void kernel_launch(void* const* d_in, const int* in_sizes, int n_in,
                              void* d_out, int out_size, void* d_ws, size_t ws_size,
                              hipStream_t stream) {
    const int*   y     = (const int*)d_in[0];
    const float* alpha = (const float*)d_in[1];
    const float* beta  = (const float*)d_in[2];
    const float* core  = (const float*)d_in[3];
    float*       out   = (float*)d_out;

    const size_t need = WS_DATA_BYTES + WS_SC_BYTES; // 200 MiB

    if (ws_size >= need) {
        unsigned int* wsd  = (unsigned int*)d_ws;
        float*        wssc = (float*)((char*)d_ws + WS_DATA_BYTES);
        squash12_kernel<<<VOCAB, 64, 0, stream>>>(core, wsd, wssc);
        mps_u12_lds_kernel<<<BATCH, 64, 0, stream>>>(y, alpha, beta, wsd, wssc, out);
    } else {
        mps_f32_kernel<<<(BATCH * 64) / 256, 256, 0, stream>>>(
            y, alpha, beta, core, out);
    }
}

// Round 10
// 568.553 us; speedup vs baseline: 1.4112x; 1.0257x over previous
//
#include <hip/hip_runtime.h>

#define RANK   64
#define VOCAB  32768
#define BATCH  2048
#define SEQLEN 256

typedef __attribute__((ext_vector_type(4))) unsigned int uint4v;

// ws layout:
//   region A (u10 data): per token v, 5 chunks x 1KB (5120B, stride 320 uint4v).
//     chunk c, lane s holds dwords D[4c..4c+3] of lane s's 20-dword blob.
//     Group gi (entries r=16gi..16gi+15) packed LSB-first into D[5gi..5gi+4].
//     entry (r,s) of matrix v: M[r][s] = scale[v][r] * u10.
//   region B (scales): f32 ws_sc[v][r], 256 B per token.
#define WS_DATA_BYTES ((size_t)VOCAB * 5120)
#define WS_SC_BYTES   ((size_t)VOCAB * 256)

// ---------------------------------------------------------------------------
// Kernel 1: squash+quantize u10. One wave per matrix. Lane s owns column s.
// Row maxima via padded LDS transpose (structure proven r8/r9).
// ---------------------------------------------------------------------------
__global__ __launch_bounds__(64) void squash10_kernel(const float* __restrict__ core,
                                                      unsigned int* __restrict__ wsd,
                                                      float* __restrict__ wssc) {
    __shared__ float tsq[64 * 65];
    __shared__ float tinv[64];

    const int v = blockIdx.x;
    const int s = threadIdx.x;

    float sq[64];
#pragma unroll
    for (int r = 0; r < 64; ++r) {
        float c = __builtin_nontemporal_load(&core[((size_t)r * VOCAB + v) * RANK + s]);
        sq[r] = c * c;
    }
#pragma unroll
    for (int r = 0; r < 64; ++r) tsq[r * 65 + s] = sq[r];
    __syncthreads();

    float mx = 0.f;
#pragma unroll
    for (int q = 0; q < 64; ++q) mx = fmaxf(mx, tsq[s * 65 + q]);
    float scale = mx * (1.0f / 1023.0f);
    float inv   = (mx > 0.f) ? (1023.0f / mx) : 0.f;
    wssc[(size_t)v * 64 + s] = scale;
    tinv[s] = inv;
    __syncthreads();

    unsigned int D[20];
#pragma unroll
    for (int gi = 0; gi < 4; ++gi) {
        unsigned int e[16];
#pragma unroll
        for (int q = 0; q < 16; ++q) {
            float qq = sq[16 * gi + q] * tinv[16 * gi + q];
            unsigned int u = (unsigned int)(qq + 0.5f);
            e[q] = (u > 1023u) ? 1023u : u;
        }
        D[5 * gi + 0] = e[0] | (e[1] << 10) | (e[2] << 20) | (e[3] << 30);
        D[5 * gi + 1] = (e[3] >> 2) | (e[4] << 8) | (e[5] << 18) | (e[6] << 28);
        D[5 * gi + 2] = (e[6] >> 4) | (e[7] << 6) | (e[8] << 16) | (e[9] << 26);
        D[5 * gi + 3] = (e[9] >> 6) | (e[10] << 4) | (e[11] << 14) | (e[12] << 24);
        D[5 * gi + 4] = (e[12] >> 8) | (e[13] << 2) | (e[14] << 12) | (e[15] << 22);
    }
    uint4v* dst = (uint4v*)wsd;
#pragma unroll
    for (int c = 0; c < 5; ++c) {
        uint4v w;
        w[0] = D[4 * c + 0]; w[1] = D[4 * c + 1];
        w[2] = D[4 * c + 2]; w[3] = D[4 * c + 3];
        dst[((size_t)v * 5 + c) * 64 + s] = w;
    }
}

// ---------------------------------------------------------------------------
// global->LDS DMA helpers
// ---------------------------------------------------------------------------
__device__ __forceinline__ void gload16(const void* g, void* l) {
    __builtin_amdgcn_global_load_lds(
        (const __attribute__((address_space(1))) void*)g,
        (__attribute__((address_space(3))) void*)l, 16, 0, 0);
}
__device__ __forceinline__ void gload4(const void* g, void* l) {
    __builtin_amdgcn_global_load_lds(
        (const __attribute__((address_space(1))) void*)g,
        (__attribute__((address_space(3))) void*)l, 4, 0, 0);
}

// ---------------------------------------------------------------------------
// Kernel 2: one wave per block, one batch element per wave. DEPTH=3 LDS ring
// (16128 B -> >=8 blocks/CU, whole grid co-resident). 6 DMA loads/step,
// 2 steps in flight -> vmcnt(12). WAR: lgkmcnt(0)+sched_barrier after each
// consume (proven r6); RAW: counted vmcnt before consume (proven r9).
// ---------------------------------------------------------------------------
__global__ __launch_bounds__(64) void mps_u10_lds_kernel(const int* __restrict__ y,
                                                         const float* __restrict__ alpha,
                                                         const float* __restrict__ beta,
                                                         const unsigned int* __restrict__ wsd,
                                                         const float* __restrict__ wssc,
                                                         float* __restrict__ out) {
    __shared__ uint4v sdat[3][5][64]; // 15360 B
    __shared__ float  ssc[3][64];     // 768 B

    const int b    = blockIdx.x;
    const int lane = threadIdx.x;
    const int* yrow = y + (size_t)b * SEQLEN;

    int yr0 = yrow[0 * 64 + lane];
    int yr1 = yrow[1 * 64 + lane];
    int yr2 = yrow[2 * 64 + lane];
    int yr3 = yrow[3 * 64 + lane];

    float a  = alpha[lane];
    float bb = beta[lane];
    float l  = a * a;
    float b2 = bb * bb;

    // all compiler-tracked VMEM retired before first DMA (exact vmcnt)
    asm volatile("" :: "v"(yr1), "v"(yr2), "v"(yr3), "v"(b2), "v"(l));

    const uint4v* wsd4 = (const uint4v*)wsd;

    auto stage = [&](int kk, int slot) {
        int c_  = kk >> 6;
        int yy  = (c_ == 0) ? yr0 : (c_ == 1) ? yr1 : (c_ == 2) ? yr2 : yr3;
        int tok = __builtin_amdgcn_readlane(yy, kk & 63);
        const uint4v* gp = wsd4 + (size_t)tok * 320 + lane;
#pragma unroll
        for (int c = 0; c < 5; ++c) gload16(gp + c * 64, &sdat[slot][c][0]);
        gload4(wssc + (size_t)tok * 64 + lane, &ssc[slot][0]);
    };

    auto consume = [&](int slot) {
        float ls = l * ssc[slot][lane];
        unsigned int D[20];
#pragma unroll
        for (int c = 0; c < 5; ++c) {
            uint4v d = sdat[slot][c][lane]; // ds_read_b128
            D[4 * c + 0] = d[0]; D[4 * c + 1] = d[1];
            D[4 * c + 2] = d[2]; D[4 * c + 3] = d[3];
        }
        float acc0 = 0.f, acc1 = 0.f, acc2 = 0.f, acc3 = 0.f;
#pragma unroll
        for (int gi = 0; gi < 4; ++gi) {
            unsigned int d0 = D[5 * gi + 0], d1 = D[5 * gi + 1],
                         d2 = D[5 * gi + 2], d3 = D[5 * gi + 3],
                         d4 = D[5 * gi + 4];
            unsigned int ee[16];
            ee[0]  = d0 & 1023u;
            ee[1]  = (d0 >> 10) & 1023u;
            ee[2]  = (d0 >> 20) & 1023u;
            ee[3]  = ((d0 >> 30) | (d1 << 2)) & 1023u;
            ee[4]  = (d1 >> 8) & 1023u;
            ee[5]  = (d1 >> 18) & 1023u;
            ee[6]  = ((d1 >> 28) | (d2 << 4)) & 1023u;
            ee[7]  = (d2 >> 6) & 1023u;
            ee[8]  = (d2 >> 16) & 1023u;
            ee[9]  = ((d2 >> 26) | (d3 << 6)) & 1023u;
            ee[10] = (d3 >> 4) & 1023u;
            ee[11] = (d3 >> 14) & 1023u;
            ee[12] = ((d3 >> 24) | (d4 << 8)) & 1023u;
            ee[13] = (d4 >> 2) & 1023u;
            ee[14] = (d4 >> 12) & 1023u;
            ee[15] = d4 >> 22;
#pragma unroll
            for (int q = 0; q < 16; ++q) {
                const int r = 16 * gi + q;
                float lr = __uint_as_float(
                    __builtin_amdgcn_readlane(__float_as_uint(ls), r));
                float mv = (float)ee[q];
                if ((q & 3) == 0)      acc0 = fmaf(lr, mv, acc0);
                else if ((q & 3) == 1) acc1 = fmaf(lr, mv, acc1);
                else if ((q & 3) == 2) acc2 = fmaf(lr, mv, acc2);
                else                   acc3 = fmaf(lr, mv, acc3);
            }
        }
        l = (acc0 + acc1) + (acc2 + acc3);
    };

    // prologue: stage steps 0,1 into slots 0,1 (12 loads outstanding)
    stage(0, 0);
    stage(1, 1);

#define STEP(S, SLOT, STSLOT)                                              \
    do {                                                                   \
        int kk = (S) + 2; kk = (kk > SEQLEN - 1) ? (SEQLEN - 1) : kk;      \
        stage(kk, (STSLOT));                                               \
        asm volatile("s_waitcnt vmcnt(12)" ::: "memory");                  \
        __builtin_amdgcn_sched_barrier(0);                                 \
        consume((SLOT));                                                   \
        asm volatile("s_waitcnt lgkmcnt(0)" ::: "memory");                 \
        __builtin_amdgcn_sched_barrier(0);                                 \
    } while (0)

#pragma unroll 1
    for (int t3 = 0; t3 < 85; ++t3) { // steps 0..254
        int s0 = 3 * t3;
        STEP(s0 + 0, 0, 2);
        STEP(s0 + 1, 1, 0);
        STEP(s0 + 2, 2, 1);
    }
    // epilogue: step 255 is in slot 0 (staged at s=253); the s=254 duplicate
    // stage (6 loads) may stay in flight below vmcnt(6).
    asm volatile("s_waitcnt vmcnt(6)" ::: "memory");
    __builtin_amdgcn_sched_barrier(0);
    consume(0);
#undef STEP

    float v = l * b2;
#pragma unroll
    for (int off = 32; off > 0; off >>= 1) v += __shfl_xor(v, off, 64);
    if (lane == 0) out[b] = v;
}

// ---------------------------------------------------------------------------
// Fallback (exact f32, direct gather from core) if ws is too small.
// ---------------------------------------------------------------------------
__global__ __launch_bounds__(256) void mps_f32_kernel(const int* __restrict__ y,
                                                      const float* __restrict__ alpha,
                                                      const float* __restrict__ beta,
                                                      const float* __restrict__ core,
                                                      float* __restrict__ out) {
    int b    = (blockIdx.x * 256 + threadIdx.x) >> 6;
    int lane = threadIdx.x & 63;
    const int* yrow = y + (size_t)b * SEQLEN;

    float a = alpha[lane];
    float l = a * a;

#pragma unroll 1
    for (int t = 0; t < SEQLEN; ++t) {
        int tok = __builtin_amdgcn_readfirstlane(yrow[t]);
        const float* p = core + (size_t)tok * RANK + lane;
        float acc[4] = {0.f, 0.f, 0.f, 0.f};
#pragma unroll
        for (int r = 0; r < 64; ++r) {
            float m  = p[(size_t)r * (VOCAB * RANK)];
            float lr = __uint_as_float(
                __builtin_amdgcn_readlane(__float_as_uint(l), r));
            acc[r & 3] = fmaf(lr, m * m, acc[r & 3]);
        }
        l = (acc[0] + acc[1]) + (acc[2] + acc[3]);
    }

    float bb = beta[lane];
    float v  = l * bb * bb;
#pragma unroll
    for (int off = 32; off > 0; off >>= 1) v += __shfl_xor(v, off, 64);
    if (lane == 0) out[b] = v;
}

extern "C" void kernel_launch(void* const* d_in, const int* in_sizes, int n_in,
                              void* d_out, int out_size, void* d_ws, size_t ws_size,
                              hipStream_t stream) {
    const int*   y     = (const int*)d_in[0];
    const float* alpha = (const float*)d_in[1];
    const float* beta  = (const float*)d_in[2];
    const float* core  = (const float*)d_in[3];
    float*       out   = (float*)d_out;

    const size_t need = WS_DATA_BYTES + WS_SC_BYTES; // 168 MiB

    if (ws_size >= need) {
        unsigned int* wsd  = (unsigned int*)d_ws;
        float*        wssc = (float*)((char*)d_ws + WS_DATA_BYTES);
        squash10_kernel<<<VOCAB, 64, 0, stream>>>(core, wsd, wssc);
        mps_u10_lds_kernel<<<BATCH, 64, 0, stream>>>(y, alpha, beta, wsd, wssc, out);
    } else {
        mps_f32_kernel<<<(BATCH * 64) / 256, 256, 0, stream>>>(
            y, alpha, beta, core, out);
    }
}